// Round 3
// baseline (186.809 us; speedup 1.0000x reference)
//
#include <hip/hip_runtime.h>
#include <hip/hip_bf16.h>
#include <stdint.h>

// StrideGraphSAGE on MI355X (gfx950).
// h_l = elu(agg @ Wl[l] + bl[l] + nodes @ Wr[l]); out = concat(h_0..h_3, x) along C.
// agg is nonzero only for rows < 1089 (un-offset edge_index bug in the reference);
// the edge set is the deterministic stride-2 grid pattern -> computed analytically.

#define C_DIM 256
#define GRID_G 33
#define N_NODES 1089
#define BATCH 64
#define TOTAL (BATCH * N_NODES)     // 69696
#define M_PAD 69760                 // 545 * 128
#define CN (C_DIM * N_NODES)        // 278784
#define OUT_STRIDE_B (5 * CN)       // 1393920
#define NCOLS 1024                  // 4 layers * 256
#define AGG_ROWS 1152               // 9*128, zero-padded past 1089

using bf16 = __hip_bfloat16;
typedef __attribute__((ext_vector_type(8))) short short8;
typedef __attribute__((ext_vector_type(4))) float f32x4;

// ---- workspace layout (bytes) ----
#define NODES_BYTES ((size_t)M_PAD * C_DIM * 2)      // 35,717,120
#define OFF_NODES   ((size_t)0)
#define OFF_AGGB    (NODES_BYTES)
#define AGGB_BYTES  ((size_t)AGG_ROWS * C_DIM * 2)   // 589,824
#define OFF_WLT     (OFF_AGGB + AGGB_BYTES)
#define WT_BYTES    ((size_t)NCOLS * C_DIM * 2)      // 524,288
#define OFF_WRT     (OFF_WLT + WT_BYTES)

__device__ __forceinline__ void gload16(void* lds, const void* g) {
    __builtin_amdgcn_global_load_lds(
        (const __attribute__((address_space(1))) uint32_t*)g,
        (__attribute__((address_space(3))) uint32_t*)lds,
        16, 0, 0);
}

// ---- fused prep: blocks 0..127 transpose W -> WT bf16; blocks 128..1279:
// x [B,C,N] f32 -> nodes [B*N, C] bf16, and copy x into out concat-block 4 ----
__global__ __launch_bounds__(256)
void prep_kernel(const float* __restrict__ x,
                 const float* __restrict__ Wl, const float* __restrict__ Wr,
                 bf16* __restrict__ nodes, bf16* __restrict__ WlT, bf16* __restrict__ WrT,
                 float* __restrict__ out)
{
    __shared__ char smem[33792];
    const int t = threadIdx.x;
    const int bid = blockIdx.x;
    if (bid < 128) {
        // ---- weight transpose: W[l][k][c] f32 -> WT[l*256+c][k] bf16 ----
        float (*tile)[65] = (float(*)[65])smem;
        const int sel = bid & 1;
        const int l = (bid >> 1) & 3;
        const int kt = ((bid >> 3) & 3) * 64;
        const int ct = ((bid >> 5) & 3) * 64;
        const float* W = sel ? Wr : Wl;
        bf16* WT = sel ? WrT : WlT;
        const int tc = t & 63;
        const int tk = t >> 6;
#pragma unroll
        for (int i = 0; i < 16; ++i) {
            int kl = i * 4 + tk;
            tile[kl][tc] = W[((size_t)(l * 256 + kt + kl)) * 256 + ct + tc];
        }
        __syncthreads();
#pragma unroll
        for (int i = 0; i < 16; ++i) {
            int cl = i * 4 + tk;
            WT[((size_t)(l * 256 + ct + cl)) * 256 + kt + tc] = __float2bfloat16(tile[tc][cl]);
        }
    } else {
        // ---- x transpose ----
        bf16 (*tile)[66] = (bf16(*)[66])smem;   // [c][n], row stride 132B
        const int bid2 = bid - 128;
        const int b = bid2 / 18;
        const int n0 = (bid2 % 18) * 64;
        const int nl = t & 63;
        const int cs = t >> 6;           // 0..3
        const int n = n0 + nl;
        const bool nvalid = n < N_NODES;
        const float* xb = x + (size_t)b * CN;
        float* outb = out + (size_t)b * OUT_STRIDE_B + (size_t)4 * CN;
#pragma unroll 4
        for (int cc = 0; cc < 64; ++cc) {
            int c = cc * 4 + cs;
            if (nvalid) {
                float v = xb[(size_t)c * N_NODES + n];
                outb[(size_t)c * N_NODES + n] = v;           // concat block 4 = x
                tile[c][nl] = __float2bfloat16(v);
            }
        }
        __syncthreads();
        const int half = t >> 7;             // 0..1
        const int c0 = (t & 127) * 2;
#pragma unroll
        for (int it = 0; it < 32; ++it) {
            int row = it * 2 + half;
            int nr = n0 + row;
            if (nr < N_NODES) {
                __hip_bfloat162 p;
                p.x = tile[c0][row];
                p.y = tile[c0 + 1][row];
                *(__hip_bfloat162*)(nodes + ((size_t)b * N_NODES + nr) * C_DIM + c0) = p;
            }
        }
    }
}

// ---- analytic mean-aggregate (replaces deg/scatter/finalize/zero) ----
// node (i,j) receives from (i,j-2) [j>=2], (i-2,j) [i>=2], (i-2,j-2) [i>=2&&j>=2],
// (i-2,j+2) [i>=2 && 1<=j<=30]. Rows 1089..1151 are zero padding.
__global__ __launch_bounds__(256)
void gather_kernel(const bf16* __restrict__ nodes, bf16* __restrict__ aggb)
{
    const int n = blockIdx.x;        // 0..1151
    const int c = threadIdx.x;
    if (n >= N_NODES) {
        aggb[(size_t)n * C_DIM + c] = __float2bfloat16(0.f);
        return;
    }
    const int i = n / GRID_G, j = n % GRID_G;
    float s = 0.f, d = 0.f;
    if (j >= 2)           { s += __bfloat162float(nodes[(size_t)(n - 2)  * C_DIM + c]); d += 1.f; }
    if (i >= 2)           { s += __bfloat162float(nodes[(size_t)(n - 66) * C_DIM + c]); d += 1.f; }
    if (i >= 2 && j >= 2) { s += __bfloat162float(nodes[(size_t)(n - 68) * C_DIM + c]); d += 1.f; }
    if (i >= 2 && j >= 1 && j <= 30)
                          { s += __bfloat162float(nodes[(size_t)(n - 64) * C_DIM + c]); d += 1.f; }
    aggb[(size_t)n * C_DIM + c] = __float2bfloat16(d > 0.f ? s / d : 0.f);
}

// ---- fused GEMM: out = elu(nodes@WrT^T + [agg@WlT^T] + bias), scrambled store ----
// 128x256 tile (BM=128, BN=256), 4 waves (2x2, each 64x128), 16x16x32 bf16 MFMA,
// 2-phase double-buffered staging, XOR-swizzled LDS (both-sides).
__global__ __launch_bounds__(256)
void gemm_kernel(const bf16* __restrict__ nodes, const bf16* __restrict__ agg,
                 const bf16* __restrict__ WrT, const bf16* __restrict__ WlT,
                 const float* __restrict__ bias, float* __restrict__ out)
{
    __shared__ bf16 Alds[2][128 * 32];
    __shared__ bf16 Blds[2][256 * 32];
    const int t = threadIdx.x;
    const int lane = t & 63;
    const int w = t >> 6;
    const int brow = blockIdx.y;
    const int bcol = blockIdx.x;       // 0..3 == output layer

    f32x4 acc[4][8] = {};

    // staging: swizzle: phys 16B slot s holds logical slot s ^ ((row>>1)&3)
    const int tq = t >> 2;                               // rows 0..63 (+64k for issue q)
    const int kk = (((t & 3) ^ ((tq >> 1) & 3)) << 3);   // row+64 preserves (row>>1)&3
    const int wr = (w >> 1) << 6;      // 0 / 64
    const int wc = (w & 1) << 7;       // 0 / 128
    const int fr = lane & 15;
    const int kq = lane >> 4;
    const int swz = (kq ^ ((fr >> 1) & 3)) << 3;         // phys slot for reads (shorts)

    char* AldsB = (char*)Alds;
    char* BldsB = (char*)Blds;
    const short* AldsS = (const short*)Alds;
    const short* BldsS = (const short*)Blds;

    const int nsteps = (brow * 128 < N_NODES) ? 16 : 8;
    const bf16* Abase0 = nodes + (size_t)brow * 128 * C_DIM;
    const bf16* Abase1 = agg + (size_t)brow * 128 * C_DIM;
    const bf16* Bbase0 = WrT + (size_t)bcol * 256 * C_DIM;
    const bf16* Bbase1 = WlT + (size_t)bcol * 256 * C_DIM;

    auto STAGE = [&](int s, int buf) {
        const int k0 = (s & 7) * 32;
        const bf16* Ag = (s < 8 ? Abase0 : Abase1) + (size_t)tq * C_DIM + k0 + kk;
        const bf16* Bg = (s < 8 ? Bbase0 : Bbase1) + (size_t)tq * C_DIM + k0 + kk;
        gload16(AldsB + buf * 8192 + w * 1024,        Ag);
        gload16(AldsB + buf * 8192 + 4096 + w * 1024, Ag + 64 * C_DIM);
#pragma unroll
        for (int q = 0; q < 4; ++q)
            gload16(BldsB + buf * 16384 + q * 4096 + w * 1024, Bg + (size_t)q * 64 * C_DIM);
    };

    STAGE(0, 0);
    __syncthreads();     // drains vmcnt before barrier
    int cur = 0;
    for (int s = 0; s < nsteps; ++s) {
        if (s + 1 < nsteps) STAGE(s + 1, cur ^ 1);   // prefetch next, in flight across MFMA
        short8 av[4];
#pragma unroll
        for (int m = 0; m < 4; ++m)
            av[m] = *(const short8*)(AldsS + cur * 4096 + (wr + m * 16 + fr) * 32 + swz);
#pragma unroll
        for (int n = 0; n < 8; ++n) {
            short8 bv = *(const short8*)(BldsS + cur * 8192 + (wc + n * 16 + fr) * 32 + swz);
#pragma unroll
            for (int m = 0; m < 4; ++m)
                acc[m][n] = __builtin_amdgcn_mfma_f32_16x16x32_bf16(
                    av[m], bv, acc[m][n], 0, 0, 0);
        }
        __syncthreads();  // my ds_reads done; prefetch drained -> safe to swap buffers
        cur ^= 1;
    }

    // epilogue: bias + fast ELU + scrambled store (layer == bcol, uniform)
    const int rq = (lane >> 4) * 4;
    const int r0 = brow * 128 + wr + rq;
    const unsigned bb0 = (unsigned)r0 / N_NODES;         // one divide per lane
    const int rsw = (int)((bb0 + 1) * N_NODES);
    float* outL = out + (size_t)bcol * CN;
    int cof[8];
    float bi[8];
#pragma unroll
    for (int n = 0; n < 8; ++n) {
        int cl = wc + n * 16 + fr;
        cof[n] = cl;
        bi[n] = bias[bcol * 256 + cl];
    }
#pragma unroll
    for (int m = 0; m < 4; ++m) {
#pragma unroll
        for (int reg = 0; reg < 4; ++reg) {
            int r = r0 + m * 16 + reg;
            if (r < TOTAL) {
                int bb = (int)bb0 + (r >= rsw ? 1 : 0);
                int nn = r - bb * N_NODES;
                size_t base = (size_t)bb * OUT_STRIDE_B + (size_t)nn * C_DIM;
#pragma unroll
                for (int n = 0; n < 8; ++n) {
                    float v = acc[m][n][reg] + bi[n];
                    v = v > 0.f ? v : (__expf(v) - 1.0f);
                    outL[base + cof[n]] = v;
                }
            }
        }
    }
}

extern "C" void kernel_launch(void* const* d_in, const int* in_sizes, int n_in,
                              void* d_out, int out_size, void* d_ws, size_t ws_size,
                              hipStream_t stream) {
    const float* x  = (const float*)d_in[0];
    const float* Wl = (const float*)d_in[1];
    const float* bl = (const float*)d_in[2];
    const float* Wr = (const float*)d_in[3];
    float* out = (float*)d_out;
    char* ws = (char*)d_ws;

    bf16* nodes = (bf16*)(ws + OFF_NODES);
    bf16* aggb  = (bf16*)(ws + OFF_AGGB);
    bf16* WlT   = (bf16*)(ws + OFF_WLT);
    bf16* WrT   = (bf16*)(ws + OFF_WRT);

    prep_kernel<<<128 + BATCH * 18, 256, 0, stream>>>(x, Wl, Wr, nodes, WlT, WrT, out);
    gather_kernel<<<AGG_ROWS, 256, 0, stream>>>(nodes, aggb);
    gemm_kernel<<<dim3(4, 545), 256, 0, stream>>>(nodes, aggb, WrT, WlT, bl, out);
}

// Round 4
// 157.000 us; speedup vs baseline: 1.1899x; 1.1899x over previous
//
#include <hip/hip_runtime.h>
#include <hip/hip_bf16.h>
#include <stdint.h>

// StrideGraphSAGE on MI355X (gfx950).
// h_l = elu(agg @ Wl[l] + bl[l] + nodes @ Wr[l]); out = concat(h_0..h_3, x) along C.
// agg is nonzero only for rows < 1089 (un-offset edge_index bug in the reference);
// the edge set is the deterministic stride-2 grid pattern -> computed analytically.

#define C_DIM 256
#define GRID_G 33
#define N_NODES 1089
#define BATCH 64
#define TOTAL (BATCH * N_NODES)     // 69696
#define M_PAD 69760                 // 545 * 128
#define CN (C_DIM * N_NODES)        // 278784
#define OUT_STRIDE_B (5 * CN)       // 1393920
#define NCOLS 1024                  // 4 layers * 256
#define AGG_ROWS 1152               // 9*128, zero-padded past 1089

using bf16 = __hip_bfloat16;
typedef __attribute__((ext_vector_type(8))) short short8;
typedef __attribute__((ext_vector_type(4))) float f32x4;

// ---- workspace layout (bytes) ----
#define NODES_BYTES ((size_t)M_PAD * C_DIM * 2)      // 35,717,120
#define OFF_NODES   ((size_t)0)
#define OFF_AGGB    (NODES_BYTES)
#define AGGB_BYTES  ((size_t)AGG_ROWS * C_DIM * 2)   // 589,824
#define OFF_WLT     (OFF_AGGB + AGGB_BYTES)
#define WT_BYTES    ((size_t)NCOLS * C_DIM * 2)      // 524,288
#define OFF_WRT     (OFF_WLT + WT_BYTES)

__device__ __forceinline__ void gload16(void* lds, const void* g) {
    __builtin_amdgcn_global_load_lds(
        (const __attribute__((address_space(1))) uint32_t*)g,
        (__attribute__((address_space(3))) uint32_t*)lds,
        16, 0, 0);
}

// ---- fused prep: blocks 0..127 transpose W -> WT bf16; blocks 128..1279:
// x [B,C,N] f32 -> nodes [B*N, C] bf16, and copy x into out concat-block 4 ----
__global__ __launch_bounds__(256)
void prep_kernel(const float* __restrict__ x,
                 const float* __restrict__ Wl, const float* __restrict__ Wr,
                 bf16* __restrict__ nodes, bf16* __restrict__ WlT, bf16* __restrict__ WrT,
                 float* __restrict__ out)
{
    __shared__ char smem[33792];
    const int t = threadIdx.x;
    const int bid = blockIdx.x;
    if (bid < 128) {
        // ---- weight transpose: W[l][k][c] f32 -> WT[l*256+c][k] bf16 ----
        float (*tile)[65] = (float(*)[65])smem;
        const int sel = bid & 1;
        const int l = (bid >> 1) & 3;
        const int kt = ((bid >> 3) & 3) * 64;
        const int ct = ((bid >> 5) & 3) * 64;
        const float* W = sel ? Wr : Wl;
        bf16* WT = sel ? WrT : WlT;
        const int tc = t & 63;
        const int tk = t >> 6;
#pragma unroll
        for (int i = 0; i < 16; ++i) {
            int kl = i * 4 + tk;
            tile[kl][tc] = W[((size_t)(l * 256 + kt + kl)) * 256 + ct + tc];
        }
        __syncthreads();
#pragma unroll
        for (int i = 0; i < 16; ++i) {
            int cl = i * 4 + tk;
            WT[((size_t)(l * 256 + ct + cl)) * 256 + kt + tc] = __float2bfloat16(tile[tc][cl]);
        }
    } else {
        // ---- x transpose ----
        bf16 (*tile)[66] = (bf16(*)[66])smem;   // [c][n], row stride 132B
        const int bid2 = bid - 128;
        const int b = bid2 / 18;
        const int n0 = (bid2 % 18) * 64;
        const int nl = t & 63;
        const int cs = t >> 6;           // 0..3
        const int n = n0 + nl;
        const bool nvalid = n < N_NODES;
        const float* xb = x + (size_t)b * CN;
        float* outb = out + (size_t)b * OUT_STRIDE_B + (size_t)4 * CN;
#pragma unroll 4
        for (int cc = 0; cc < 64; ++cc) {
            int c = cc * 4 + cs;
            if (nvalid) {
                float v = xb[(size_t)c * N_NODES + n];
                outb[(size_t)c * N_NODES + n] = v;           // concat block 4 = x
                tile[c][nl] = __float2bfloat16(v);
            }
        }
        __syncthreads();
        const int half = t >> 7;             // 0..1
        const int c0 = (t & 127) * 2;
#pragma unroll
        for (int it = 0; it < 32; ++it) {
            int row = it * 2 + half;
            int nr = n0 + row;
            if (nr < N_NODES) {
                __hip_bfloat162 p;
                p.x = tile[c0][row];
                p.y = tile[c0 + 1][row];
                *(__hip_bfloat162*)(nodes + ((size_t)b * N_NODES + nr) * C_DIM + c0) = p;
            }
        }
    }
}

// ---- analytic mean-aggregate ----
// node (i,j) receives from (i,j-2) [j>=2], (i-2,j) [i>=2], (i-2,j-2) [i>=2&&j>=2],
// (i-2,j+2) [i>=2 && 1<=j<=30]. Rows 1089..1151 are zero padding.
__global__ __launch_bounds__(256)
void gather_kernel(const bf16* __restrict__ nodes, bf16* __restrict__ aggb)
{
    const int n = blockIdx.x;        // 0..1151
    const int c = threadIdx.x;
    if (n >= N_NODES) {
        aggb[(size_t)n * C_DIM + c] = __float2bfloat16(0.f);
        return;
    }
    const int i = n / GRID_G, j = n % GRID_G;
    float s = 0.f, d = 0.f;
    if (j >= 2)           { s += __bfloat162float(nodes[(size_t)(n - 2)  * C_DIM + c]); d += 1.f; }
    if (i >= 2)           { s += __bfloat162float(nodes[(size_t)(n - 66) * C_DIM + c]); d += 1.f; }
    if (i >= 2 && j >= 2) { s += __bfloat162float(nodes[(size_t)(n - 68) * C_DIM + c]); d += 1.f; }
    if (i >= 2 && j >= 1 && j <= 30)
                          { s += __bfloat162float(nodes[(size_t)(n - 64) * C_DIM + c]); d += 1.f; }
    aggb[(size_t)n * C_DIM + c] = __float2bfloat16(d > 0.f ? s / d : 0.f);
}

// ---- fused GEMM: out = elu(nodes@WrT^T + [agg@WlT^T] + bias), scrambled store ----
// 128x128 tile, 4 waves, 16x16x32 bf16 MFMA. 3-buffer LDS, 2-deep prefetch with
// counted s_waitcnt vmcnt(4) + raw s_barrier (never drains to 0 in steady state).
// XOR-swizzled LDS both-sides. XCD-aware block swizzle (nwg = 4360 = 8*545).
__global__ __launch_bounds__(256)
void gemm_kernel(const bf16* __restrict__ nodes, const bf16* __restrict__ agg,
                 const bf16* __restrict__ WrT, const bf16* __restrict__ WlT,
                 const float* __restrict__ bias, float* __restrict__ out)
{
    __shared__ bf16 Alds[3][128 * 32];
    __shared__ bf16 Blds[3][128 * 32];
    const int t = threadIdx.x;
    const int lane = t & 63;
    const int w = t >> 6;
    // XCD swizzle: XCD k (bid%8==k) gets contiguous swz range -> ~68 brows x all
    // 8 bcols per XCD -> A panels L2-resident, B (1MB) L2-resident.
    const unsigned bid = blockIdx.x;
    const unsigned swz = (bid & 7) * 545 + (bid >> 3);
    const int bcol = swz & 7;
    const int brow = swz >> 3;

    f32x4 acc[4][4] = {};

    // staging: phys 16B slot s holds logical slot s ^ ((row>>1)&3)
    const int tq = t >> 2;                               // rows 0..63 (+64 for issue 1)
    const int kk = (((t & 3) ^ ((tq >> 1) & 3)) << 3);
    const int wr = (w >> 1) << 6;
    const int wc = (w & 1) << 6;
    const int fr = lane & 15;
    const int kq = lane >> 4;
    const int swzr = (kq ^ ((fr >> 1) & 3)) << 3;        // phys slot for reads (shorts)

    char* AldsB = (char*)Alds;
    char* BldsB = (char*)Blds;
    const short* AldsS = (const short*)Alds;
    const short* BldsS = (const short*)Blds;

    const int nsteps = (brow * 128 < N_NODES) ? 16 : 8;
    const bf16* Abase0 = nodes + (size_t)brow * 128 * C_DIM;
    const bf16* Abase1 = agg + (size_t)brow * 128 * C_DIM;
    const bf16* Bbase0 = WrT + (size_t)bcol * 128 * C_DIM;
    const bf16* Bbase1 = WlT + (size_t)bcol * 128 * C_DIM;

    auto STAGE = [&](int s, int buf) {
        const int k0 = (s & 7) * 32;
        const bf16* Ag = (s < 8 ? Abase0 : Abase1) + (size_t)tq * C_DIM + k0 + kk;
        const bf16* Bg = (s < 8 ? Bbase0 : Bbase1) + (size_t)tq * C_DIM + k0 + kk;
        gload16(AldsB + buf * 8192 + w * 1024,        Ag);
        gload16(AldsB + buf * 8192 + 4096 + w * 1024, Ag + 64 * C_DIM);
        gload16(BldsB + buf * 8192 + w * 1024,        Bg);
        gload16(BldsB + buf * 8192 + 4096 + w * 1024, Bg + 64 * C_DIM);
    };

    STAGE(0, 0);
    STAGE(1, 1);                       // 8 vmem ops in flight
    int rb = 0;                        // buffer read at step s; (rb+2)%3 is write target
    for (int s = 0; s < nsteps; ++s) {
        // wait only for STAGE(s); STAGE(s+1)'s 4 ops stay in flight across barrier
        if (s + 1 < nsteps) asm volatile("s_waitcnt vmcnt(4)" ::: "memory");
        else                asm volatile("s_waitcnt vmcnt(0)" ::: "memory");
        __builtin_amdgcn_s_barrier();
        if (s + 2 < nsteps) STAGE(s + 2, rb == 0 ? 2 : (rb == 1 ? 0 : 1));
        const short* Ab = AldsS + rb * 4096;
        const short* Bb = BldsS + rb * 4096;
        short8 av[4], bv[4];
#pragma unroll
        for (int m = 0; m < 4; ++m)
            av[m] = *(const short8*)(Ab + (wr + m * 16 + fr) * 32 + swzr);
#pragma unroll
        for (int n = 0; n < 4; ++n)
            bv[n] = *(const short8*)(Bb + (wc + n * 16 + fr) * 32 + swzr);
#pragma unroll
        for (int m = 0; m < 4; ++m)
#pragma unroll
            for (int n = 0; n < 4; ++n)
                acc[m][n] = __builtin_amdgcn_mfma_f32_16x16x32_bf16(
                    av[m], bv[n], acc[m][n], 0, 0, 0);
        rb = (rb == 2) ? 0 : rb + 1;
    }

    // epilogue: bias + fast ELU + scrambled store
    const int rq = (lane >> 4) * 4;
    const int r0 = brow * 128 + wr + rq;
    const unsigned bb0 = (unsigned)r0 / N_NODES;         // one divide per lane
    const int rsw = (int)((bb0 + 1) * N_NODES);
    const int colbase = bcol * 128 + wc + fr;
    size_t coff[4];
    float bi[4];
#pragma unroll
    for (int n = 0; n < 4; ++n) {
        int col = colbase + n * 16;
        coff[n] = (size_t)(col >> 8) * CN + (col & 255);
        bi[n] = bias[col];
    }
#pragma unroll
    for (int m = 0; m < 4; ++m) {
#pragma unroll
        for (int reg = 0; reg < 4; ++reg) {
            int r = r0 + m * 16 + reg;
            if (r < TOTAL) {
                int bb = (int)bb0 + (r >= rsw ? 1 : 0);
                int nn = r - bb * N_NODES;
                size_t base = (size_t)bb * OUT_STRIDE_B + (size_t)nn * C_DIM;
#pragma unroll
                for (int n = 0; n < 4; ++n) {
                    float v = acc[m][n][reg] + bi[n];
                    v = v > 0.f ? v : (__expf(v) - 1.0f);
                    out[base + coff[n]] = v;
                }
            }
        }
    }
}

extern "C" void kernel_launch(void* const* d_in, const int* in_sizes, int n_in,
                              void* d_out, int out_size, void* d_ws, size_t ws_size,
                              hipStream_t stream) {
    const float* x  = (const float*)d_in[0];
    const float* Wl = (const float*)d_in[1];
    const float* bl = (const float*)d_in[2];
    const float* Wr = (const float*)d_in[3];
    float* out = (float*)d_out;
    char* ws = (char*)d_ws;

    bf16* nodes = (bf16*)(ws + OFF_NODES);
    bf16* aggb  = (bf16*)(ws + OFF_AGGB);
    bf16* WlT   = (bf16*)(ws + OFF_WLT);
    bf16* WrT   = (bf16*)(ws + OFF_WRT);

    prep_kernel<<<128 + BATCH * 18, 256, 0, stream>>>(x, Wl, Wr, nodes, WlT, WrT, out);
    gather_kernel<<<AGG_ROWS, 256, 0, stream>>>(nodes, aggb);
    gemm_kernel<<<8 * 545, 256, 0, stream>>>(nodes, aggb, WrT, WlT, bl, out);
}